// Round 4
// baseline (301.081 us; speedup 1.0000x reference)
//
#include <hip/hip_runtime.h>
#include <math.h>

#define N_NODES 100000
#define N_EDGES 1200000
#define DIM 64
#define ELL_STRIDE 48        // ints per node row; deg<=48 safe (Poisson(12))
#define BNODES 128           // nodes per bucket (dst>>7)
#define NBUCKET ((N_NODES + BNODES - 1) / BNODES)   // 782 buckets
#define BIN_SHIFT 10         // coarse bin = dst>>10 (1024 nodes)
#define NBIN ((N_NODES + 1023) >> 10)               // 98 bins
#define BIN_CAP 16384        // edges per bin region; mean 12245, +37 sigma
#define CAP 40               // staged edges per bin per fill block; mean 23.9, +3.3 sigma
#define BIN_BLOCKS 512
#define EPB ((N_EDGES + BIN_BLOCKS - 1) / BIN_BLOCKS)  // 2344 edges/block
#define GEMM_BLOCKS ((N_NODES + 63) / 64)      // 1563 (64 nodes/block)

// packed edge: bits 0-16 = src (<131072), bits 17-26 = dst & 1023
#define PACK(s, dloc) (((unsigned)(dloc) << 17) | (unsigned)(s))
#define UNPACK_S(p)   ((int)((p) & 0x1FFFF))
#define UNPACK_D(p)   ((int)((p) >> 17))

// bf16 pack/unpack (RTNE)
__device__ __forceinline__ unsigned short f2bf(float f) {
    union { float f; unsigned int u; } v; v.f = f;
    unsigned int r = v.u + 0x7FFF + ((v.u >> 16) & 1);
    return (unsigned short)(r >> 16);
}
__device__ __forceinline__ float bf2f(unsigned short us) {
    return __uint_as_float((unsigned int)us << 16);
}

// ---------------- init: zero the 98 bin tails (1 line apart) ----------------

__global__ void k_init(int* __restrict__ tail) {
    if (threadIdx.x < NBIN) tail[threadIdx.x * 16] = 0;
}

// ---------------- gemm tile: 64 nodes/block, LDS-staged x, W in VGPRs -------

__device__ __forceinline__ void gemm_block(int bid, const float* __restrict__ x,
                                           const float* __restrict__ W,
                                           unsigned short* __restrict__ h,
                                           float4* __restrict__ Xlds) {
    const int tid = threadIdx.x;
    const int lane = tid & 63;

    float wreg[64];                         // W column for this lane (L2-hot)
#pragma unroll
    for (int k = 0; k < 64; ++k) wreg[k] = W[k * DIM + lane];

    const int base = bid * 64;
#pragma unroll
    for (int it = 0; it < 4; ++it) {
        int f = tid + it * 256;             // float4 index in tile
        int row = base + (f >> 4);
        if (row >= N_NODES) row = N_NODES - 1;          // clamp (value unused)
        Xlds[f] = ((const float4*)x)[row * 16 + (f & 15)];
    }
    __syncthreads();

    const int m0 = (tid >> 6) * 16;         // wave's 16 rows
    for (int m = 0; m < 16; ++m) {
        const float4* xr = &Xlds[(m0 + m) * 16];
        float a0 = 0.f, a1 = 0.f, a2 = 0.f, a3 = 0.f;
#pragma unroll
        for (int k4 = 0; k4 < 16; ++k4) {
            float4 xv = xr[k4];             // uniform b128 broadcast
            a0 = fmaf(xv.x, wreg[k4 * 4 + 0], a0);
            a1 = fmaf(xv.y, wreg[k4 * 4 + 1], a1);
            a2 = fmaf(xv.z, wreg[k4 * 4 + 2], a2);
            a3 = fmaf(xv.w, wreg[k4 * 4 + 3], a3);
        }
        int row = base + m0 + m;
        if (row < N_NODES)
            h[(size_t)row * DIM + lane] = f2bf((a0 + a1) + (a2 + a3));
    }
}

// ---------------- fused: gemm1 (blocks 0..1562)  ||  LDS-staged binning -----
// Fill blocks stage PACKED edges (u32) into 98 coarse bins in LDS, then flush
// each bin as one contiguous segment. u32 staging keeps the union at 16.4 KB
// (vs 31.4 KB int2 last round, which throttled the gemm phase to 4 blocks/CU).

__global__ void __launch_bounds__(256) k_pre(const int* __restrict__ ei,
                                             const float* __restrict__ x,
                                             const float* __restrict__ W1,
                                             int* __restrict__ tail,
                                             unsigned* __restrict__ part,
                                             unsigned short* __restrict__ h) {
    __shared__ __align__(16) char smraw[16384];   // union: gemm tile / u32 staging (15.7 KB)
    __shared__ int lcnt[NBIN];
    __shared__ int gbase[NBIN];
    __shared__ int gcnt[NBIN];

    if (blockIdx.x < GEMM_BLOCKS) {
        gemm_block(blockIdx.x, x, W1, h, (float4*)smraw);
        return;
    }
    unsigned* stg = (unsigned*)smraw;
    const int tid = threadIdx.x;
    for (int i = tid; i < NBIN; i += 256) lcnt[i] = 0;
    __syncthreads();

    const int e0 = (blockIdx.x - GEMM_BLOCKS) * EPB;
    const int eend = (e0 + EPB < N_EDGES) ? e0 + EPB : N_EDGES;
    for (int e = e0 + tid; e < eend; e += 256) {
        int s = ei[e], d = ei[N_EDGES + e];
        int bin = d >> BIN_SHIFT;
        unsigned pk = PACK(s, d & 1023);
        int pos = atomicAdd(&lcnt[bin], 1);
        if (pos < CAP) {
            stg[bin * CAP + pos] = pk;
        } else {                              // ~3.3-sigma tail, few hundred edges
            int gp = atomicAdd(&tail[bin * 16], 1);
            part[(size_t)bin * BIN_CAP + gp] = pk;
        }
    }
    __syncthreads();
    if (tid < NBIN) {
        int c = lcnt[tid]; if (c > CAP) c = CAP;
        gcnt[tid] = c;
        gbase[tid] = c ? atomicAdd(&tail[tid * 16], c) : 0;
    }
    __syncthreads();
    const int wv = tid >> 6, ln = tid & 63;   // wave-parallel flush (4 bins concurrent)
    for (int b = wv; b < NBIN; b += 4) {
        int c = gcnt[b];
        size_t gbb = (size_t)b * BIN_CAP + gbase[b];
        for (int i = ln; i < c; i += 64)
            part[gbb + i] = stg[b * CAP + i];
    }
}

// ---------------- bucket build: ELL slab in LDS + fused h1 scale ------------

__global__ void __launch_bounds__(256) k_bucket(const unsigned* __restrict__ part,
                                                const int* __restrict__ tail,
                                                int* __restrict__ ell,
                                                int* __restrict__ deg,
                                                unsigned short* __restrict__ hA,
                                                unsigned short* __restrict__ hB) {
    __shared__ int lcur[BNODES];
    __shared__ int lell[BNODES * ELL_STRIDE];   // 24 KB
    const int bucket = blockIdx.x;
    const int tid = threadIdx.x;

    for (int i = tid; i < BNODES; i += 256) lcur[i] = 0;
    __syncthreads();

    const int bin = bucket >> 3;                // dst>>10 == (dst>>7)>>3
    const int sub = bucket & 7;
    const int n = tail[bin * 16];
    const unsigned* pb = part + (size_t)bin * BIN_CAP;
    const int node0 = bucket * BNODES;
    for (int i = tid; i < n; i += 256) {
        unsigned p = pb[i];
        unsigned ld = (unsigned)(UNPACK_D(p) - (sub << 7));
        if (ld < BNODES) {
            int pos = atomicAdd(&lcur[ld], 1);
            if (pos < ELL_STRIDE) lell[ld * ELL_STRIDE + pos] = UNPACK_S(p);
        }
    }
    __syncthreads();

    for (int idx = tid; idx < BNODES * ELL_STRIDE; idx += 256) {
        int ln = idx / ELL_STRIDE, sl = idx - ln * ELL_STRIDE;
        int dg = lcur[ln];
        int pe = (dg + 7) & ~7;
        if (pe < 16) pe = 16;
        if (sl >= dg && sl < pe) lell[idx] = N_NODES;   // dummy zero row
    }
    __syncthreads();

    int4* dst4 = (int4*)(ell + (size_t)bucket * BNODES * ELL_STRIDE);
    const int4* src4 = (const int4*)lell;
    for (int i = tid; i < BNODES * ELL_STRIDE / 4; i += 256) dst4[i] = src4[i];
    for (int i = tid; i < BNODES; i += 256) deg[node0 + i] = lcur[i];

    // fused scale: hA[row] *= dinv; zero both dummy rows
    for (int i = tid; i < BNODES * 8; i += 256) {       // 8 uint4 per row
        int ln = i >> 3;
        int node = node0 + ln;
        if (node < N_NODES) {
            float dd = rsqrtf((float)(lcur[ln] + 1));
            uint4* p = (uint4*)(hA + (size_t)node * DIM) + (i & 7);
            uint4 v = *p;
            float lo, hi;
            lo = __uint_as_float(v.x << 16) * dd; hi = __uint_as_float(v.x & 0xFFFF0000u) * dd;
            v.x = (unsigned)f2bf(lo) | ((unsigned)f2bf(hi) << 16);
            lo = __uint_as_float(v.y << 16) * dd; hi = __uint_as_float(v.y & 0xFFFF0000u) * dd;
            v.y = (unsigned)f2bf(lo) | ((unsigned)f2bf(hi) << 16);
            lo = __uint_as_float(v.z << 16) * dd; hi = __uint_as_float(v.z & 0xFFFF0000u) * dd;
            v.z = (unsigned)f2bf(lo) | ((unsigned)f2bf(hi) << 16);
            lo = __uint_as_float(v.w << 16) * dd; hi = __uint_as_float(v.w & 0xFFFF0000u) * dd;
            v.w = (unsigned)f2bf(lo) | ((unsigned)f2bf(hi) << 16);
            *p = v;
        }
    }
    if (bucket == 0) {
        if (tid < 8)  ((uint4*)(hA + (size_t)N_NODES * DIM))[tid] = make_uint4(0, 0, 0, 0);
        else if (tid < 16) ((uint4*)(hB + (size_t)N_NODES * DIM))[tid - 8] = make_uint4(0, 0, 0, 0);
    }
}

// ---------------- shared gather body: acc for one node ---------------------

__device__ __forceinline__ float gather_acc(const unsigned short* __restrict__ h,
                                            const int* __restrict__ row,
                                            int node, int lane, int dg) {
    int4 e0 = ((const int4*)row)[0];
    int4 e1 = ((const int4*)row)[1];
    int4 e2 = ((const int4*)row)[2];
    int4 e3 = ((const int4*)row)[3];
    float own = bf2f(h[(size_t)node * DIM + lane]);

    float v0  = bf2f(h[(size_t)e0.x * DIM + lane]);
    float v1  = bf2f(h[(size_t)e0.y * DIM + lane]);
    float v2  = bf2f(h[(size_t)e0.z * DIM + lane]);
    float v3  = bf2f(h[(size_t)e0.w * DIM + lane]);
    float v4  = bf2f(h[(size_t)e1.x * DIM + lane]);
    float v5  = bf2f(h[(size_t)e1.y * DIM + lane]);
    float v6  = bf2f(h[(size_t)e1.z * DIM + lane]);
    float v7  = bf2f(h[(size_t)e1.w * DIM + lane]);
    float v8  = bf2f(h[(size_t)e2.x * DIM + lane]);
    float v9  = bf2f(h[(size_t)e2.y * DIM + lane]);
    float v10 = bf2f(h[(size_t)e2.z * DIM + lane]);
    float v11 = bf2f(h[(size_t)e2.w * DIM + lane]);
    float v12 = bf2f(h[(size_t)e3.x * DIM + lane]);
    float v13 = bf2f(h[(size_t)e3.y * DIM + lane]);
    float v14 = bf2f(h[(size_t)e3.z * DIM + lane]);
    float v15 = bf2f(h[(size_t)e3.w * DIM + lane]);

    float acc = ((own + v0) + (v1 + v2)) + ((v3 + v4) + (v5 + v6))
              + ((v7 + v8) + (v9 + v10)) + ((v11 + v12) + ((v13 + v14) + v15));

    if (dg > 16) {                          // rare, wave-uniform
        int pe = (dg + 7) & ~7;
        for (int k = 16; k < pe; k += 8) {
            int4 a = *(const int4*)(row + k);
            int4 c = *(const int4*)(row + k + 4);
            float w0 = bf2f(h[(size_t)a.x * DIM + lane]);
            float w1 = bf2f(h[(size_t)a.y * DIM + lane]);
            float w2 = bf2f(h[(size_t)a.z * DIM + lane]);
            float w3 = bf2f(h[(size_t)a.w * DIM + lane]);
            float w4 = bf2f(h[(size_t)c.x * DIM + lane]);
            float w5 = bf2f(h[(size_t)c.y * DIM + lane]);
            float w6 = bf2f(h[(size_t)c.z * DIM + lane]);
            float w7 = bf2f(h[(size_t)c.w * DIM + lane]);
            acc += ((w0 + w1) + (w2 + w3)) + ((w4 + w5) + (w6 + w7));
        }
    }
    return acc;
}

// ---------------- fused gather+GEMM: agg -> +b -> relu -> @W -> *dinv -------
// 64 nodes/block, 4 waves x 16 nodes. Unroll 4 -> ~68 scattered h-loads in
// flight per wave (latency-bound random access; round-3 measured 1.36 TB/s
// effective fetch at unroll 2).

__global__ void __launch_bounds__(256, 4)
k_gatherW(const unsigned short* __restrict__ h,
          const int* __restrict__ deg,
          const int* __restrict__ ell,
          const float* __restrict__ bvec,
          const float* __restrict__ W,
          unsigned short* __restrict__ hout) {
    __shared__ float sh[64 * 64];               // 16 KB agg rows
    __shared__ float sdd[64];                   // dinv cache for phase 2
    const int tid = threadIdx.x;
    const int lane = tid & 63;
    const int wv = tid >> 6;
    const int base = blockIdx.x * 64;
    const float bl = bvec[lane];

#pragma unroll 4
    for (int m = 0; m < 16; ++m) {
        int node = base + wv * 16 + m;
        if (node >= N_NODES) node = 0;          // tail block; store guarded below
        int dg = __builtin_amdgcn_readfirstlane(deg[node]);
        const int* row = ell + (size_t)node * ELL_STRIDE;

        float acc = gather_acc(h, row, node, lane, dg);

        float dd = rsqrtf((float)(dg + 1));
        float o = fmaxf(fmaf(acc, dd, bl), 0.f);    // bias + relu (layers 1,2)
        sh[(wv * 16 + m) * 64 + lane] = o;          // banks: 2-way, free
        if (lane == 0) sdd[wv * 16 + m] = dd;
    }

    // phase 2: row @ W, scaled by dinv[row] (wreg loaded late)
    float wreg[64];
#pragma unroll
    for (int k = 0; k < 64; ++k) wreg[k] = W[k * DIM + lane];

#pragma unroll 4
    for (int m = 0; m < 16; ++m) {
        const float4* xr = (const float4*)&sh[(wv * 16 + m) * 64];
        float a0 = 0.f, a1 = 0.f, a2 = 0.f, a3 = 0.f;
#pragma unroll
        for (int k4 = 0; k4 < 16; ++k4) {
            float4 xv = xr[k4];                 // uniform broadcast read
            a0 = fmaf(xv.x, wreg[k4 * 4 + 0], a0);
            a1 = fmaf(xv.y, wreg[k4 * 4 + 1], a1);
            a2 = fmaf(xv.z, wreg[k4 * 4 + 2], a2);
            a3 = fmaf(xv.w, wreg[k4 * 4 + 3], a3);
        }
        int rown = base + wv * 16 + m;
        if (rown < N_NODES) {
            float res = (a0 + a1) + (a2 + a3);
            res *= sdd[wv * 16 + m];
            hout[(size_t)rown * DIM + lane] = f2bf(res);
        }
    }
}

// ---------------- final gather: out = dinv*(sum) + b (fp32) -----------------
// Same 16-nodes-per-wave unrolled structure for memory pipelining.

__global__ void __launch_bounds__(256, 4)
k_gatherF(const unsigned short* __restrict__ h,
          const int* __restrict__ deg,
          const int* __restrict__ ell, const float* __restrict__ bvec,
          float* __restrict__ out) {
    const int tid = threadIdx.x;
    const int lane = tid & 63;
    const int wv = tid >> 6;
    const int base = blockIdx.x * 64;
    const float bl = bvec[lane];

#pragma unroll 4
    for (int m = 0; m < 16; ++m) {
        int node = base + wv * 16 + m;
        bool valid = node < N_NODES;
        if (!valid) node = 0;
        int dg = __builtin_amdgcn_readfirstlane(deg[node]);
        const int* row = ell + (size_t)node * ELL_STRIDE;

        float acc = gather_acc(h, row, node, lane, dg);

        float dd = rsqrtf((float)(dg + 1));
        if (valid) out[(size_t)node * DIM + lane] = fmaf(acc, dd, bl);
    }
}

// ---------------- launch ----------------

extern "C" void kernel_launch(void* const* d_in, const int* in_sizes, int n_in,
                              void* d_out, int out_size, void* d_ws, size_t ws_size,
                              hipStream_t stream) {
    const float* x   = (const float*)d_in[0];
    const int*   ei  = (const int*)d_in[1];     // [2, E] row-major
    const float* W1  = (const float*)d_in[2];
    const float* b1  = (const float*)d_in[3];
    const float* W2  = (const float*)d_in[4];
    const float* b2  = (const float*)d_in[5];
    const float* W3  = (const float*)d_in[6];
    const float* b3  = (const float*)d_in[7];
    float* out = (float*)d_out;

    // ws layout; part (u32, 6.4 MB) overlays hbufB (disjoint lifetimes)
    char* ws = (char*)d_ws;
    int*            deg   = (int*)ws;                           // 400 KB
    int*            tailp = (int*)(ws + 0x70000);               // 98 x 64B
    int*            ell   = (int*)(ws + 0xD00000);              // 19.2 MB
    unsigned short* hbufA = (unsigned short*)(ws + 0x2000000);  // 12.8 MB (+dummy)
    unsigned short* hbufB = (unsigned short*)(ws + 0x2D00000);  // 12.85 MB
    unsigned*       part  = (unsigned*)(ws + 0x2D00000);        // overlay (NBIN*BIN_CAP*4)

    k_init<<<1, 128, 0, stream>>>(tailp);

    // gemm1 (x @ W1 -> hbufA, unscaled)  ||  LDS-binned edge partition
    k_pre<<<GEMM_BLOCKS + BIN_BLOCKS, 256, 0, stream>>>(ei, x, W1, tailp, part, hbufA);
    // bucket ELL build + deg + fused hbufA scale + dummy-row zeroing
    k_bucket<<<NBUCKET, 256, 0, stream>>>(part, tailp, ell, deg, hbufA, hbufB);

    // Layer 1->2: gather(h1') + b1 + relu -> @W2 *dinv -> hbufB
    k_gatherW<<<GEMM_BLOCKS, 256, 0, stream>>>(hbufA, deg, ell, b1, W2, hbufB);
    // Layer 2->3: -> @W3 *dinv -> hbufA
    k_gatherW<<<GEMM_BLOCKS, 256, 0, stream>>>(hbufB, deg, ell, b2, W3, hbufA);
    // Layer 3 final: fp32 out
    k_gatherF<<<GEMM_BLOCKS, 256, 0, stream>>>(hbufA, deg, ell, b3, out);
}

// Round 5
// 267.475 us; speedup vs baseline: 1.1256x; 1.1256x over previous
//
#include <hip/hip_runtime.h>
#include <math.h>

#define N_NODES 100000
#define N_EDGES 1200000
#define DIM 64
#define ELL_STRIDE 48        // ints per node row; deg<=48 safe (Poisson(12))
#define BNODES 128           // nodes per bucket (dst>>7)
#define NBUCKET ((N_NODES + BNODES - 1) / BNODES)   // 782 buckets
#define BIN_SHIFT 10         // coarse bin = dst>>10 (1024 nodes)
#define NBIN ((N_NODES + 1023) >> 10)               // 98 bins
#define BIN_CAP 16384        // edges per bin region; mean 12245, +37 sigma
#define CAP 40               // staged edges per bin per fill block; mean 23.9, +3.3 sigma
#define BIN_BLOCKS 512
#define EPB ((N_EDGES + BIN_BLOCKS - 1) / BIN_BLOCKS)  // 2344 edges/block
#define GEMM_BLOCKS ((N_NODES + 63) / 64)      // 1563 (64 nodes/block)
#define GW_BLOCKS (N_NODES / 16)               // 6250 (16 nodes/block, exact)

// packed edge: bits 0-16 = src (<131072), bits 17-26 = dst & 1023
#define PACK(s, dloc) (((unsigned)(dloc) << 17) | (unsigned)(s))
#define UNPACK_S(p)   ((int)((p) & 0x1FFFF))
#define UNPACK_D(p)   ((int)((p) >> 17))

// bf16 pack/unpack (RTNE)
__device__ __forceinline__ unsigned short f2bf(float f) {
    union { float f; unsigned int u; } v; v.f = f;
    unsigned int r = v.u + 0x7FFF + ((v.u >> 16) & 1);
    return (unsigned short)(r >> 16);
}
__device__ __forceinline__ float bf2f(unsigned short us) {
    return __uint_as_float((unsigned int)us << 16);
}

// ---------------- init: zero the 98 bin tails (1 line apart) ----------------

__global__ void k_init(int* __restrict__ tail) {
    if (threadIdx.x < NBIN) tail[threadIdx.x * 16] = 0;
}

// ---------------- gemm tile: 64 nodes/block, LDS-staged x, W in VGPRs -------

__device__ __forceinline__ void gemm_block(int bid, const float* __restrict__ x,
                                           const float* __restrict__ W,
                                           unsigned short* __restrict__ h,
                                           float4* __restrict__ Xlds) {
    const int tid = threadIdx.x;
    const int lane = tid & 63;

    float wreg[64];                         // W column for this lane (L2-hot)
#pragma unroll
    for (int k = 0; k < 64; ++k) wreg[k] = W[k * DIM + lane];

    const int base = bid * 64;
#pragma unroll
    for (int it = 0; it < 4; ++it) {
        int f = tid + it * 256;             // float4 index in tile
        int row = base + (f >> 4);
        if (row >= N_NODES) row = N_NODES - 1;          // clamp (value unused)
        Xlds[f] = ((const float4*)x)[row * 16 + (f & 15)];
    }
    __syncthreads();

    const int m0 = (tid >> 6) * 16;         // wave's 16 rows
    for (int m = 0; m < 16; ++m) {
        const float4* xr = &Xlds[(m0 + m) * 16];
        float a0 = 0.f, a1 = 0.f, a2 = 0.f, a3 = 0.f;
#pragma unroll
        for (int k4 = 0; k4 < 16; ++k4) {
            float4 xv = xr[k4];             // uniform b128 broadcast
            a0 = fmaf(xv.x, wreg[k4 * 4 + 0], a0);
            a1 = fmaf(xv.y, wreg[k4 * 4 + 1], a1);
            a2 = fmaf(xv.z, wreg[k4 * 4 + 2], a2);
            a3 = fmaf(xv.w, wreg[k4 * 4 + 3], a3);
        }
        int row = base + m0 + m;
        if (row < N_NODES)
            h[(size_t)row * DIM + lane] = f2bf((a0 + a1) + (a2 + a3));
    }
}

// ---------------- fused: gemm1 (blocks 0..1562)  ||  LDS-staged binning -----

__global__ void __launch_bounds__(256) k_pre(const int* __restrict__ ei,
                                             const float* __restrict__ x,
                                             const float* __restrict__ W1,
                                             int* __restrict__ tail,
                                             unsigned* __restrict__ part,
                                             unsigned short* __restrict__ h) {
    __shared__ __align__(16) char smraw[16384];   // union: gemm tile / u32 staging (15.7 KB)
    __shared__ int lcnt[NBIN];
    __shared__ int gbase[NBIN];
    __shared__ int gcnt[NBIN];

    if (blockIdx.x < GEMM_BLOCKS) {
        gemm_block(blockIdx.x, x, W1, h, (float4*)smraw);
        return;
    }
    unsigned* stg = (unsigned*)smraw;
    const int tid = threadIdx.x;
    for (int i = tid; i < NBIN; i += 256) lcnt[i] = 0;
    __syncthreads();

    const int e0 = (blockIdx.x - GEMM_BLOCKS) * EPB;
    const int eend = (e0 + EPB < N_EDGES) ? e0 + EPB : N_EDGES;
    for (int e = e0 + tid; e < eend; e += 256) {
        int s = ei[e], d = ei[N_EDGES + e];
        int bin = d >> BIN_SHIFT;
        unsigned pk = PACK(s, d & 1023);
        int pos = atomicAdd(&lcnt[bin], 1);
        if (pos < CAP) {
            stg[bin * CAP + pos] = pk;
        } else {                              // ~3.3-sigma tail, few hundred edges
            int gp = atomicAdd(&tail[bin * 16], 1);
            part[(size_t)bin * BIN_CAP + gp] = pk;
        }
    }
    __syncthreads();
    if (tid < NBIN) {
        int c = lcnt[tid]; if (c > CAP) c = CAP;
        gcnt[tid] = c;
        gbase[tid] = c ? atomicAdd(&tail[tid * 16], c) : 0;
    }
    __syncthreads();
    const int wv = tid >> 6, ln = tid & 63;   // wave-parallel flush (4 bins concurrent)
    for (int b = wv; b < NBIN; b += 4) {
        int c = gcnt[b];
        size_t gbb = (size_t)b * BIN_CAP + gbase[b];
        for (int i = ln; i < c; i += 64)
            part[gbb + i] = stg[b * CAP + i];
    }
}

// ---------------- bucket build: ELL slab in LDS + fused h1 scale ------------

__global__ void __launch_bounds__(256) k_bucket(const unsigned* __restrict__ part,
                                                const int* __restrict__ tail,
                                                int* __restrict__ ell,
                                                int* __restrict__ deg,
                                                unsigned short* __restrict__ hA,
                                                unsigned short* __restrict__ hB) {
    __shared__ int lcur[BNODES];
    __shared__ int lell[BNODES * ELL_STRIDE];   // 24 KB
    const int bucket = blockIdx.x;
    const int tid = threadIdx.x;

    for (int i = tid; i < BNODES; i += 256) lcur[i] = 0;
    __syncthreads();

    const int bin = bucket >> 3;                // dst>>10 == (dst>>7)>>3
    const int sub = bucket & 7;
    const int n = tail[bin * 16];
    const unsigned* pb = part + (size_t)bin * BIN_CAP;
    const int node0 = bucket * BNODES;
    for (int i = tid; i < n; i += 256) {
        unsigned p = pb[i];
        unsigned ld = (unsigned)(UNPACK_D(p) - (sub << 7));
        if (ld < BNODES) {
            int pos = atomicAdd(&lcur[ld], 1);
            if (pos < ELL_STRIDE) lell[ld * ELL_STRIDE + pos] = UNPACK_S(p);
        }
    }
    __syncthreads();

    for (int idx = tid; idx < BNODES * ELL_STRIDE; idx += 256) {
        int ln = idx / ELL_STRIDE, sl = idx - ln * ELL_STRIDE;
        int dg = lcur[ln];
        int pe = (dg + 7) & ~7;
        if (pe < 16) pe = 16;
        if (sl >= dg && sl < pe) lell[idx] = N_NODES;   // dummy zero row
    }
    __syncthreads();

    int4* dst4 = (int4*)(ell + (size_t)bucket * BNODES * ELL_STRIDE);
    const int4* src4 = (const int4*)lell;
    for (int i = tid; i < BNODES * ELL_STRIDE / 4; i += 256) dst4[i] = src4[i];
    for (int i = tid; i < BNODES; i += 256) deg[node0 + i] = lcur[i];

    // fused scale: hA[row] *= dinv; zero both dummy rows
    for (int i = tid; i < BNODES * 8; i += 256) {       // 8 uint4 per row
        int ln = i >> 3;
        int node = node0 + ln;
        if (node < N_NODES) {
            float dd = rsqrtf((float)(lcur[ln] + 1));
            uint4* p = (uint4*)(hA + (size_t)node * DIM) + (i & 7);
            uint4 v = *p;
            float lo, hi;
            lo = __uint_as_float(v.x << 16) * dd; hi = __uint_as_float(v.x & 0xFFFF0000u) * dd;
            v.x = (unsigned)f2bf(lo) | ((unsigned)f2bf(hi) << 16);
            lo = __uint_as_float(v.y << 16) * dd; hi = __uint_as_float(v.y & 0xFFFF0000u) * dd;
            v.y = (unsigned)f2bf(lo) | ((unsigned)f2bf(hi) << 16);
            lo = __uint_as_float(v.z << 16) * dd; hi = __uint_as_float(v.z & 0xFFFF0000u) * dd;
            v.z = (unsigned)f2bf(lo) | ((unsigned)f2bf(hi) << 16);
            lo = __uint_as_float(v.w << 16) * dd; hi = __uint_as_float(v.w & 0xFFFF0000u) * dd;
            v.w = (unsigned)f2bf(lo) | ((unsigned)f2bf(hi) << 16);
            *p = v;
        }
    }
    if (bucket == 0) {
        if (tid < 8)  ((uint4*)(hA + (size_t)N_NODES * DIM))[tid] = make_uint4(0, 0, 0, 0);
        else if (tid < 16) ((uint4*)(hB + (size_t)N_NODES * DIM))[tid - 8] = make_uint4(0, 0, 0, 0);
    }
}

// ---------------- fused gather+GEMM: agg -> +b -> relu -> @W -> *dinv -------
// 16 nodes/block (4 waves x 4 nodes), 6250 blocks. Small blocks -> ~5
// resident blocks/CU (vs ~2.6 at 64-node blocks) -> 2x outstanding misses.
// Round-3 inline gather body verbatim (known-good codegen: VGPR 64,
// VALUBusy 55%); round-4's refactor+unroll-4 regressed it (VGPR 52, 39%).

__global__ void __launch_bounds__(256, 4)
k_gatherW(const unsigned short* __restrict__ h,
          const int* __restrict__ deg,
          const int* __restrict__ ell,
          const float* __restrict__ bvec,
          const float* __restrict__ W,
          unsigned short* __restrict__ hout) {
    __shared__ float sh[16 * 64];               // 4 KB agg rows
    const int tid = threadIdx.x;
    const int lane = tid & 63;
    const int wv = tid >> 6;
    const int base = blockIdx.x * 16;           // 6250*16 = 100000 exact
    const float bl = bvec[lane];

#pragma unroll 2
    for (int m = 0; m < 4; ++m) {
        int node = base + wv * 4 + m;
        int dg = __builtin_amdgcn_readfirstlane(deg[node]);
        const int* row = ell + (size_t)node * ELL_STRIDE;

        int4 e0 = ((const int4*)row)[0];
        int4 e1 = ((const int4*)row)[1];
        int4 e2 = ((const int4*)row)[2];
        int4 e3 = ((const int4*)row)[3];
        float own = bf2f(h[(size_t)node * DIM + lane]);

        float v0  = bf2f(h[(size_t)e0.x * DIM + lane]);
        float v1  = bf2f(h[(size_t)e0.y * DIM + lane]);
        float v2  = bf2f(h[(size_t)e0.z * DIM + lane]);
        float v3  = bf2f(h[(size_t)e0.w * DIM + lane]);
        float v4  = bf2f(h[(size_t)e1.x * DIM + lane]);
        float v5  = bf2f(h[(size_t)e1.y * DIM + lane]);
        float v6  = bf2f(h[(size_t)e1.z * DIM + lane]);
        float v7  = bf2f(h[(size_t)e1.w * DIM + lane]);
        float v8  = bf2f(h[(size_t)e2.x * DIM + lane]);
        float v9  = bf2f(h[(size_t)e2.y * DIM + lane]);
        float v10 = bf2f(h[(size_t)e2.z * DIM + lane]);
        float v11 = bf2f(h[(size_t)e2.w * DIM + lane]);
        float v12 = bf2f(h[(size_t)e3.x * DIM + lane]);
        float v13 = bf2f(h[(size_t)e3.y * DIM + lane]);
        float v14 = bf2f(h[(size_t)e3.z * DIM + lane]);
        float v15 = bf2f(h[(size_t)e3.w * DIM + lane]);

        float acc = ((own + v0) + (v1 + v2)) + ((v3 + v4) + (v5 + v6))
                  + ((v7 + v8) + (v9 + v10)) + ((v11 + v12) + ((v13 + v14) + v15));

        if (dg > 16) {                          // rare, wave-uniform
            int pe = (dg + 7) & ~7;
            for (int k = 16; k < pe; k += 8) {
                int4 a = *(const int4*)(row + k);
                int4 c = *(const int4*)(row + k + 4);
                float w0 = bf2f(h[(size_t)a.x * DIM + lane]);
                float w1 = bf2f(h[(size_t)a.y * DIM + lane]);
                float w2 = bf2f(h[(size_t)a.z * DIM + lane]);
                float w3 = bf2f(h[(size_t)a.w * DIM + lane]);
                float w4 = bf2f(h[(size_t)c.x * DIM + lane]);
                float w5 = bf2f(h[(size_t)c.y * DIM + lane]);
                float w6 = bf2f(h[(size_t)c.z * DIM + lane]);
                float w7 = bf2f(h[(size_t)c.w * DIM + lane]);
                acc += ((w0 + w1) + (w2 + w3)) + ((w4 + w5) + (w6 + w7));
            }
        }

        float dd = rsqrtf((float)(dg + 1));
        float o = fmaxf(fmaf(acc, dd, bl), 0.f);    // bias + relu (layers 1,2)
        sh[(wv * 4 + m) * 64 + lane] = o;           // banks: 2-way, free
    }

    // phase 2: row @ W, scaled by dinv[row] (wreg loaded late)
    float wreg[64];
#pragma unroll
    for (int k = 0; k < 64; ++k) wreg[k] = W[k * DIM + lane];

#pragma unroll
    for (int m = 0; m < 4; ++m) {
        const float4* xr = (const float4*)&sh[(wv * 4 + m) * 64];
        float a0 = 0.f, a1 = 0.f, a2 = 0.f, a3 = 0.f;
#pragma unroll
        for (int k4 = 0; k4 < 16; ++k4) {
            float4 xv = xr[k4];                 // uniform broadcast read
            a0 = fmaf(xv.x, wreg[k4 * 4 + 0], a0);
            a1 = fmaf(xv.y, wreg[k4 * 4 + 1], a1);
            a2 = fmaf(xv.z, wreg[k4 * 4 + 2], a2);
            a3 = fmaf(xv.w, wreg[k4 * 4 + 3], a3);
        }
        int rown = base + wv * 4 + m;
        float res = (a0 + a1) + (a2 + a3);
        res *= rsqrtf((float)(deg[rown] + 1));
        hout[(size_t)rown * DIM + lane] = f2bf(res);
    }
}

// ---------------- final gather: out = dinv*(sum) + b (fp32) -----------------
// Round-2 form: 1 node/wave, 25000 blocks (measured < 48 us — best TLP).

__global__ void k_gatherF(const unsigned short* __restrict__ h,
                          const int* __restrict__ deg,
                          const int* __restrict__ ell, const float* __restrict__ b,
                          float* __restrict__ out) {
    int node = blockIdx.x * 4 + (threadIdx.x >> 6);     // 25000*4 = 100000 exact
    const int lane = threadIdx.x & 63;
    int dg = __builtin_amdgcn_readfirstlane(deg[node]);
    const int* row = ell + (size_t)node * ELL_STRIDE;

    int4 e0 = ((const int4*)row)[0];
    int4 e1 = ((const int4*)row)[1];
    int4 e2 = ((const int4*)row)[2];
    int4 e3 = ((const int4*)row)[3];
    float own = bf2f(h[(size_t)node * DIM + lane]);

    float v0  = bf2f(h[(size_t)e0.x * DIM + lane]);
    float v1  = bf2f(h[(size_t)e0.y * DIM + lane]);
    float v2  = bf2f(h[(size_t)e0.z * DIM + lane]);
    float v3  = bf2f(h[(size_t)e0.w * DIM + lane]);
    float v4  = bf2f(h[(size_t)e1.x * DIM + lane]);
    float v5  = bf2f(h[(size_t)e1.y * DIM + lane]);
    float v6  = bf2f(h[(size_t)e1.z * DIM + lane]);
    float v7  = bf2f(h[(size_t)e1.w * DIM + lane]);
    float v8  = bf2f(h[(size_t)e2.x * DIM + lane]);
    float v9  = bf2f(h[(size_t)e2.y * DIM + lane]);
    float v10 = bf2f(h[(size_t)e2.z * DIM + lane]);
    float v11 = bf2f(h[(size_t)e2.w * DIM + lane]);
    float v12 = bf2f(h[(size_t)e3.x * DIM + lane]);
    float v13 = bf2f(h[(size_t)e3.y * DIM + lane]);
    float v14 = bf2f(h[(size_t)e3.z * DIM + lane]);
    float v15 = bf2f(h[(size_t)e3.w * DIM + lane]);

    float acc = ((own + v0) + (v1 + v2)) + ((v3 + v4) + (v5 + v6))
              + ((v7 + v8) + (v9 + v10)) + ((v11 + v12) + ((v13 + v14) + v15));

    if (dg > 16) {
        int pe = (dg + 7) & ~7;
        for (int k = 16; k < pe; k += 8) {
            int4 a = *(const int4*)(row + k);
            int4 c = *(const int4*)(row + k + 4);
            float w0 = bf2f(h[(size_t)a.x * DIM + lane]);
            float w1 = bf2f(h[(size_t)a.y * DIM + lane]);
            float w2 = bf2f(h[(size_t)a.z * DIM + lane]);
            float w3 = bf2f(h[(size_t)a.w * DIM + lane]);
            float w4 = bf2f(h[(size_t)c.x * DIM + lane]);
            float w5 = bf2f(h[(size_t)c.y * DIM + lane]);
            float w6 = bf2f(h[(size_t)c.z * DIM + lane]);
            float w7 = bf2f(h[(size_t)c.w * DIM + lane]);
            acc += ((w0 + w1) + (w2 + w3)) + ((w4 + w5) + (w6 + w7));
        }
    }

    float dd = rsqrtf((float)(dg + 1));
    out[(size_t)node * DIM + lane] = fmaf(acc, dd, b[lane]);
}

// ---------------- launch ----------------

extern "C" void kernel_launch(void* const* d_in, const int* in_sizes, int n_in,
                              void* d_out, int out_size, void* d_ws, size_t ws_size,
                              hipStream_t stream) {
    const float* x   = (const float*)d_in[0];
    const int*   ei  = (const int*)d_in[1];     // [2, E] row-major
    const float* W1  = (const float*)d_in[2];
    const float* b1  = (const float*)d_in[3];
    const float* W2  = (const float*)d_in[4];
    const float* b2  = (const float*)d_in[5];
    const float* W3  = (const float*)d_in[6];
    const float* b3  = (const float*)d_in[7];
    float* out = (float*)d_out;

    // ws layout; part (u32, 6.4 MB) overlays hbufB (disjoint lifetimes)
    char* ws = (char*)d_ws;
    int*            deg   = (int*)ws;                           // 400 KB
    int*            tailp = (int*)(ws + 0x70000);               // 98 x 64B
    int*            ell   = (int*)(ws + 0xD00000);              // 19.2 MB
    unsigned short* hbufA = (unsigned short*)(ws + 0x2000000);  // 12.8 MB (+dummy)
    unsigned short* hbufB = (unsigned short*)(ws + 0x2D00000);  // 12.85 MB
    unsigned*       part  = (unsigned*)(ws + 0x2D00000);        // overlay (NBIN*BIN_CAP*4)

    k_init<<<1, 128, 0, stream>>>(tailp);

    // gemm1 (x @ W1 -> hbufA, unscaled)  ||  LDS-binned edge partition
    k_pre<<<GEMM_BLOCKS + BIN_BLOCKS, 256, 0, stream>>>(ei, x, W1, tailp, part, hbufA);
    // bucket ELL build + deg + fused hbufA scale + dummy-row zeroing
    k_bucket<<<NBUCKET, 256, 0, stream>>>(part, tailp, ell, deg, hbufA, hbufB);

    // Layer 1->2: gather(h1') + b1 + relu -> @W2 *dinv -> hbufB
    k_gatherW<<<GW_BLOCKS, 256, 0, stream>>>(hbufA, deg, ell, b1, W2, hbufB);
    // Layer 2->3: -> @W3 *dinv -> hbufA
    k_gatherW<<<GW_BLOCKS, 256, 0, stream>>>(hbufB, deg, ell, b2, W3, hbufA);
    // Layer 3 final: fp32 out
    k_gatherF<<<N_NODES / 4, 256, 0, stream>>>(hbufA, deg, ell, b3, out);
}

// Round 7
// 245.973 us; speedup vs baseline: 1.2240x; 1.0874x over previous
//
#include <hip/hip_runtime.h>
#include <math.h>

#define N_NODES 100000
#define N_EDGES 1200000
#define DIM 64
#define ELL_STRIDE 48        // ints per node row; deg<=48 safe (Poisson(12))
#define BNODES 128           // nodes per bucket (dst>>7)
#define NBUCKET ((N_NODES + BNODES - 1) / BNODES)   // 782 buckets
#define BIN_SHIFT 10         // coarse bin = dst>>10 (1024 nodes)
#define NBIN ((N_NODES + 1023) >> 10)               // 98 bins
#define BIN_CAP 16384        // edges per bin region; mean 12245, +37 sigma
#define CAP 40               // staged edges per bin per fill block; mean 23.9, +3.3 sigma
#define BIN_BLOCKS 512
#define EPB ((N_EDGES + BIN_BLOCKS - 1) / BIN_BLOCKS)  // 2344 edges/block
#define GEMM_BLOCKS ((N_NODES + 63) / 64)      // 1563 (64 nodes/block)
#define GW_BLOCKS (N_NODES / 16)               // 6250 (16 nodes/block, exact)

// packed edge: bits 0-16 = src (<131072), bits 17-26 = dst & 1023
#define PACK(s, dloc) (((unsigned)(dloc) << 17) | (unsigned)(s))
#define UNPACK_S(p)   ((int)((p) & 0x1FFFF))
#define UNPACK_D(p)   ((int)((p) >> 17))

typedef __attribute__((ext_vector_type(8))) short bf16x8;
typedef __attribute__((ext_vector_type(4))) float f32x4;

// bf16 pack/unpack (RTNE)
__device__ __forceinline__ unsigned short f2bf(float f) {
    union { float f; unsigned int u; } v; v.f = f;
    unsigned int r = v.u + 0x7FFF + ((v.u >> 16) & 1);
    return (unsigned short)(r >> 16);
}
__device__ __forceinline__ float bf2f(unsigned short us) {
    return __uint_as_float((unsigned int)us << 16);
}

// gather load: ell stores BYTE offsets (src*128); addr = h + (off + 2*lane)
// -> one 32-bit v_add + saddr-form global_load_ushort (1 VALU/load vs ~3)
#define LDH(boff) bf2f(*(const unsigned short*)((const char*)h + ((unsigned)(boff) + bo)))

// ---------------- init: zero the 98 bin tails (1 line apart) ----------------

__global__ void k_init(int* __restrict__ tail) {
    if (threadIdx.x < NBIN) tail[threadIdx.x * 16] = 0;
}

// ---------------- gemm tile: 64 nodes/block, LDS-staged x, W in VGPRs -------

__device__ __forceinline__ void gemm_block(int bid, const float* __restrict__ x,
                                           const float* __restrict__ W,
                                           unsigned short* __restrict__ h,
                                           float4* __restrict__ Xlds) {
    const int tid = threadIdx.x;
    const int lane = tid & 63;

    float wreg[64];                         // W column for this lane (L2-hot)
#pragma unroll
    for (int k = 0; k < 64; ++k) wreg[k] = W[k * DIM + lane];

    const int base = bid * 64;
#pragma unroll
    for (int it = 0; it < 4; ++it) {
        int f = tid + it * 256;             // float4 index in tile
        int row = base + (f >> 4);
        if (row >= N_NODES) row = N_NODES - 1;          // clamp (value unused)
        Xlds[f] = ((const float4*)x)[row * 16 + (f & 15)];
    }
    __syncthreads();

    const int m0 = (tid >> 6) * 16;         // wave's 16 rows
    for (int m = 0; m < 16; ++m) {
        const float4* xr = &Xlds[(m0 + m) * 16];
        float a0 = 0.f, a1 = 0.f, a2 = 0.f, a3 = 0.f;
#pragma unroll
        for (int k4 = 0; k4 < 16; ++k4) {
            float4 xv = xr[k4];             // uniform b128 broadcast
            a0 = fmaf(xv.x, wreg[k4 * 4 + 0], a0);
            a1 = fmaf(xv.y, wreg[k4 * 4 + 1], a1);
            a2 = fmaf(xv.z, wreg[k4 * 4 + 2], a2);
            a3 = fmaf(xv.w, wreg[k4 * 4 + 3], a3);
        }
        int row = base + m0 + m;
        if (row < N_NODES)
            h[(size_t)row * DIM + lane] = f2bf((a0 + a1) + (a2 + a3));
    }
}

// ---------------- fused: gemm1 (blocks 0..1562)  ||  LDS-staged binning -----

__global__ void __launch_bounds__(256) k_pre(const int* __restrict__ ei,
                                             const float* __restrict__ x,
                                             const float* __restrict__ W1,
                                             int* __restrict__ tail,
                                             unsigned* __restrict__ part,
                                             unsigned short* __restrict__ h) {
    __shared__ __align__(16) char smraw[16384];   // union: gemm tile / u32 staging (15.7 KB)
    __shared__ int lcnt[NBIN];
    __shared__ int gbase[NBIN];
    __shared__ int gcnt[NBIN];

    if (blockIdx.x < GEMM_BLOCKS) {
        gemm_block(blockIdx.x, x, W1, h, (float4*)smraw);
        return;
    }
    unsigned* stg = (unsigned*)smraw;
    const int tid = threadIdx.x;
    for (int i = tid; i < NBIN; i += 256) lcnt[i] = 0;
    __syncthreads();

    const int e0 = (blockIdx.x - GEMM_BLOCKS) * EPB;
    const int eend = (e0 + EPB < N_EDGES) ? e0 + EPB : N_EDGES;
    for (int e = e0 + tid; e < eend; e += 256) {
        int s = ei[e], d = ei[N_EDGES + e];
        int bin = d >> BIN_SHIFT;
        unsigned pk = PACK(s, d & 1023);
        int pos = atomicAdd(&lcnt[bin], 1);
        if (pos < CAP) {
            stg[bin * CAP + pos] = pk;
        } else {                              // ~3.3-sigma tail, few hundred edges
            int gp = atomicAdd(&tail[bin * 16], 1);
            part[(size_t)bin * BIN_CAP + gp] = pk;
        }
    }
    __syncthreads();
    if (tid < NBIN) {
        int c = lcnt[tid]; if (c > CAP) c = CAP;
        gcnt[tid] = c;
        gbase[tid] = c ? atomicAdd(&tail[tid * 16], c) : 0;
    }
    __syncthreads();
    const int wv = tid >> 6, ln = tid & 63;   // wave-parallel flush (4 bins concurrent)
    for (int b = wv; b < NBIN; b += 4) {
        int c = gcnt[b];
        size_t gbb = (size_t)b * BIN_CAP + gbase[b];
        for (int i = ln; i < c; i += 64)
            part[gbb + i] = stg[b * CAP + i];
    }
}

// ---------------- bucket build: ELL slab in LDS + fused h1 scale ------------
// ELL entries are BYTE offsets into h (src * DIM * 2 = src << 7).

__global__ void __launch_bounds__(256) k_bucket(const unsigned* __restrict__ part,
                                                const int* __restrict__ tail,
                                                int* __restrict__ ell,
                                                int* __restrict__ deg,
                                                unsigned short* __restrict__ hA,
                                                unsigned short* __restrict__ hB) {
    __shared__ int lcur[BNODES];
    __shared__ int lell[BNODES * ELL_STRIDE];   // 24 KB
    const int bucket = blockIdx.x;
    const int tid = threadIdx.x;

    for (int i = tid; i < BNODES; i += 256) lcur[i] = 0;
    __syncthreads();

    const int bin = bucket >> 3;                // dst>>10 == (dst>>7)>>3
    const int sub = bucket & 7;
    const int n = tail[bin * 16];
    const unsigned* pb = part + (size_t)bin * BIN_CAP;
    const int node0 = bucket * BNODES;
    for (int i = tid; i < n; i += 256) {
        unsigned p = pb[i];
        unsigned ld = (unsigned)(UNPACK_D(p) - (sub << 7));
        if (ld < BNODES) {
            int pos = atomicAdd(&lcur[ld], 1);
            if (pos < ELL_STRIDE) lell[ld * ELL_STRIDE + pos] = UNPACK_S(p) << 7;
        }
    }
    __syncthreads();

    for (int idx = tid; idx < BNODES * ELL_STRIDE; idx += 256) {
        int ln = idx / ELL_STRIDE, sl = idx - ln * ELL_STRIDE;
        int dg = lcur[ln];
        int pe = (dg + 7) & ~7;
        if (pe < 16) pe = 16;
        if (sl >= dg && sl < pe) lell[idx] = N_NODES << 7;   // dummy zero row
    }
    __syncthreads();

    int4* dst4 = (int4*)(ell + (size_t)bucket * BNODES * ELL_STRIDE);
    const int4* src4 = (const int4*)lell;
    for (int i = tid; i < BNODES * ELL_STRIDE / 4; i += 256) dst4[i] = src4[i];
    for (int i = tid; i < BNODES; i += 256) deg[node0 + i] = lcur[i];

    // fused scale: hA[row] *= dinv; zero both dummy rows
    for (int i = tid; i < BNODES * 8; i += 256) {       // 8 uint4 per row
        int ln = i >> 3;
        int node = node0 + ln;
        if (node < N_NODES) {
            float dd = rsqrtf((float)(lcur[ln] + 1));
            uint4* p = (uint4*)(hA + (size_t)node * DIM) + (i & 7);
            uint4 v = *p;
            float lo, hi;
            lo = __uint_as_float(v.x << 16) * dd; hi = __uint_as_float(v.x & 0xFFFF0000u) * dd;
            v.x = (unsigned)f2bf(lo) | ((unsigned)f2bf(hi) << 16);
            lo = __uint_as_float(v.y << 16) * dd; hi = __uint_as_float(v.y & 0xFFFF0000u) * dd;
            v.y = (unsigned)f2bf(lo) | ((unsigned)f2bf(hi) << 16);
            lo = __uint_as_float(v.z << 16) * dd; hi = __uint_as_float(v.z & 0xFFFF0000u) * dd;
            v.z = (unsigned)f2bf(lo) | ((unsigned)f2bf(hi) << 16);
            lo = __uint_as_float(v.w << 16) * dd; hi = __uint_as_float(v.w & 0xFFFF0000u) * dd;
            v.w = (unsigned)f2bf(lo) | ((unsigned)f2bf(hi) << 16);
            *p = v;
        }
    }
    if (bucket == 0) {
        if (tid < 8)  ((uint4*)(hA + (size_t)N_NODES * DIM))[tid] = make_uint4(0, 0, 0, 0);
        else if (tid < 16) ((uint4*)(hB + (size_t)N_NODES * DIM))[tid - 8] = make_uint4(0, 0, 0, 0);
    }
}

// ---------------- fused gather+GEMM: agg -> +b -> relu -> @W(MFMA) -> *dinv -
// 16 nodes/block (4 waves x 4 nodes), 6250 blocks (round-5 TLP shape).
// Phase 2: 16x64 agg @ 64x64 W via mfma_f32_16x16x32_bf16. A and W split
// into bf16 hi+lo (AhBh + AlBh + AhBl) -> fp32-level accuracy. A and B
// fragments packed with the SAME K-slot convention (A/B lane->k layouts are
// symmetric for this instruction), so the contraction is permutation-safe.
// C/D: col=lane&15, row=(lane>>4)*4+r (HW-verified). A-tile in LDS
// chunk-XOR swizzled (16B chunk ^= row&7) to break the stride-128B
// bank conflict on fragment reads.

__global__ void __launch_bounds__(256, 4)
k_gatherW(const unsigned short* __restrict__ h,
          const int* __restrict__ deg,
          const int* __restrict__ ell,
          const float* __restrict__ bvec,
          const float* __restrict__ W,
          unsigned short* __restrict__ hout) {
    __shared__ unsigned short shb[2048];        // [0..1023] A-hi, [1024..2047] A-lo
    const int tid = threadIdx.x;
    const int lane = tid & 63;
    const int wv = tid >> 6;
    const int base = blockIdx.x * 16;           // 6250*16 = 100000 exact
    const float bl = bvec[lane];
    const unsigned bo = 2u * (unsigned)lane;

#pragma unroll 2
    for (int m = 0; m < 4; ++m) {
        int node = base + wv * 4 + m;
        int dg = __builtin_amdgcn_readfirstlane(deg[node]);
        const int* row = ell + (size_t)node * ELL_STRIDE;

        int4 e0 = ((const int4*)row)[0];
        int4 e1 = ((const int4*)row)[1];
        int4 e2 = ((const int4*)row)[2];
        int4 e3 = ((const int4*)row)[3];
        float own = LDH((unsigned)node * 128u);

        float v0  = LDH(e0.x);
        float v1  = LDH(e0.y);
        float v2  = LDH(e0.z);
        float v3  = LDH(e0.w);
        float v4  = LDH(e1.x);
        float v5  = LDH(e1.y);
        float v6  = LDH(e1.z);
        float v7  = LDH(e1.w);
        float v8  = LDH(e2.x);
        float v9  = LDH(e2.y);
        float v10 = LDH(e2.z);
        float v11 = LDH(e2.w);
        float v12 = LDH(e3.x);
        float v13 = LDH(e3.y);
        float v14 = LDH(e3.z);
        float v15 = LDH(e3.w);

        float acc = ((own + v0) + (v1 + v2)) + ((v3 + v4) + (v5 + v6))
                  + ((v7 + v8) + (v9 + v10)) + ((v11 + v12) + ((v13 + v14) + v15));

        if (dg > 16) {                          // rare, wave-uniform
            int pe = (dg + 7) & ~7;
            for (int k = 16; k < pe; k += 8) {
                int4 a = *(const int4*)(row + k);
                int4 c = *(const int4*)(row + k + 4);
                float w0 = LDH(a.x);
                float w1 = LDH(a.y);
                float w2 = LDH(a.z);
                float w3 = LDH(a.w);
                float w4 = LDH(c.x);
                float w5 = LDH(c.y);
                float w6 = LDH(c.z);
                float w7 = LDH(c.w);
                acc += ((w0 + w1) + (w2 + w3)) + ((w4 + w5) + (w6 + w7));
            }
        }

        float dd = rsqrtf((float)(dg + 1));
        float o = fmaxf(fmaf(acc, dd, bl), 0.f);    // bias + relu (layers 1,2)
        // split-bf16 store, chunk-swizzled: chunk = lane>>3, phys = chunk^(row&7)
        unsigned short oh = f2bf(o);
        unsigned short ol = f2bf(o - bf2f(oh));
        int r16 = wv * 4 + m;
        int pc = r16 * 64 + (((lane >> 3) ^ (r16 & 7)) << 3) + (lane & 7);
        shb[pc] = oh;
        shb[1024 + pc] = ol;
    }
    __syncthreads();

    // B fragments: wave wv covers output cols [wv*16, wv*16+16). K-slot
    // convention: lane l supplies k = (l>>4)*8 + j (j=0..7) per 32-K half.
    const int bcol = wv * 16 + (lane & 15);
    const int g = lane >> 4;
    bf16x8 bh0, bl0, bh1, bl1;
#pragma unroll
    for (int j = 0; j < 8; ++j) {
        float w0 = W[(g * 8 + j) * DIM + bcol];
        float w1 = W[(g * 8 + j + 32) * DIM + bcol];
        unsigned short h0 = f2bf(w0);
        unsigned short h1 = f2bf(w1);
        bh0[j] = (short)h0; bl0[j] = (short)f2bf(w0 - bf2f(h0));
        bh1[j] = (short)h1; bl1[j] = (short)f2bf(w1 - bf2f(h1));
    }

    // A fragments: row = lane&15, same K-slot convention; undo chunk swizzle
    const int arow = lane & 15;
    const int cs = arow & 7;
    bf16x8 ah0 = *(const bf16x8*)&shb[arow * 64 + ((g ^ cs) << 3)];
    bf16x8 ah1 = *(const bf16x8*)&shb[arow * 64 + (((g + 4) ^ cs) << 3)];
    bf16x8 al0 = *(const bf16x8*)&shb[1024 + arow * 64 + ((g ^ cs) << 3)];
    bf16x8 al1 = *(const bf16x8*)&shb[1024 + arow * 64 + (((g + 4) ^ cs) << 3)];

    f32x4 acc = {0.f, 0.f, 0.f, 0.f};
    acc = __builtin_amdgcn_mfma_f32_16x16x32_bf16(ah0, bh0, acc, 0, 0, 0);
    acc = __builtin_amdgcn_mfma_f32_16x16x32_bf16(ah1, bh1, acc, 0, 0, 0);
    acc = __builtin_amdgcn_mfma_f32_16x16x32_bf16(al0, bh0, acc, 0, 0, 0);
    acc = __builtin_amdgcn_mfma_f32_16x16x32_bf16(al1, bh1, acc, 0, 0, 0);
    acc = __builtin_amdgcn_mfma_f32_16x16x32_bf16(ah0, bl0, acc, 0, 0, 0);
    acc = __builtin_amdgcn_mfma_f32_16x16x32_bf16(ah1, bl1, acc, 0, 0, 0);

#pragma unroll
    for (int r = 0; r < 4; ++r) {
        int rr = g * 4 + r;                     // C/D: row=(lane>>4)*4+r
        float res = acc[r] * rsqrtf((float)(deg[base + rr] + 1));
        hout[(size_t)(base + rr) * DIM + wv * 16 + (lane & 15)] = f2bf(res);
    }
}

// ---------------- final gather: out = dinv*(sum) + b (fp32) -----------------
// 1 node/wave, 25000 blocks (best-TLP shape); byte-offset ell loads.

__global__ void k_gatherF(const unsigned short* __restrict__ h,
                          const int* __restrict__ deg,
                          const int* __restrict__ ell, const float* __restrict__ b,
                          float* __restrict__ out) {
    int node = blockIdx.x * 4 + (threadIdx.x >> 6);     // 25000*4 = 100000 exact
    const int lane = threadIdx.x & 63;
    const unsigned bo = 2u * (unsigned)lane;
    int dg = __builtin_amdgcn_readfirstlane(deg[node]);
    const int* row = ell + (size_t)node * ELL_STRIDE;

    int4 e0 = ((const int4*)row)[0];
    int4 e1 = ((const int4*)row)[1];
    int4 e2 = ((const int4*)row)[2];
    int4 e3 = ((const int4*)row)[3];
    float own = LDH((unsigned)node * 128u);

    float v0  = LDH(e0.x);
    float v1  = LDH(e0.y);
    float v2  = LDH(e0.z);
    float v3  = LDH(e0.w);
    float v4  = LDH(e1.x);
    float v5  = LDH(e1.y);
    float v6  = LDH(e1.z);
    float v7  = LDH(e1.w);
    float v8  = LDH(e2.x);
    float v9  = LDH(e2.y);
    float v10 = LDH(e2.z);
    float v11 = LDH(e2.w);
    float v12 = LDH(e3.x);
    float v13 = LDH(e3.y);
    float v14 = LDH(e3.z);
    float v15 = LDH(e3.w);

    float acc = ((own + v0) + (v1 + v2)) + ((v3 + v4) + (v5 + v6))
              + ((v7 + v8) + (v9 + v10)) + ((v11 + v12) + ((v13 + v14) + v15));

    if (dg > 16) {
        int pe = (dg + 7) & ~7;
        for (int k = 16; k < pe; k += 8) {
            int4 a = *(const int4*)(row + k);
            int4 c = *(const int4*)(row + k + 4);
            float w0 = LDH(a.x);
            float w1 = LDH(a.y);
            float w2 = LDH(a.z);
            float w3 = LDH(a.w);
            float w4 = LDH(c.x);
            float w5 = LDH(c.y);
            float w6 = LDH(c.z);
            float w7 = LDH(c.w);
            acc += ((w0 + w1) + (w2 + w3)) + ((w4 + w5) + (w6 + w7));
        }
    }

    float dd = rsqrtf((float)(dg + 1));
    out[(size_t)node * DIM + lane] = fmaf(acc, dd, b[lane]);
}

// ---------------- launch ----------------

extern "C" void kernel_launch(void* const* d_in, const int* in_sizes, int n_in,
                              void* d_out, int out_size, void* d_ws, size_t ws_size,
                              hipStream_t stream) {
    const float* x   = (const float*)d_in[0];
    const int*   ei  = (const int*)d_in[1];     // [2, E] row-major
    const float* W1  = (const float*)d_in[2];
    const float* b1  = (const float*)d_in[3];
    const float* W2  = (const float*)d_in[4];
    const float* b2  = (const float*)d_in[5];
    const float* W3  = (const float*)d_in[6];
    const float* b3  = (const float*)d_in[7];
    float* out = (float*)d_out;

    // ws layout; part (u32, 6.4 MB) overlays hbufB (disjoint lifetimes)
    char* ws = (char*)d_ws;
    int*            deg   = (int*)ws;                           // 400 KB
    int*            tailp = (int*)(ws + 0x70000);               // 98 x 64B
    int*            ell   = (int*)(ws + 0xD00000);              // 19.2 MB
    unsigned short* hbufA = (unsigned short*)(ws + 0x2000000);  // 12.8 MB (+dummy)
    unsigned short* hbufB = (unsigned short*)(ws + 0x2D00000);  // 12.85 MB
    unsigned*       part  = (unsigned*)(ws + 0x2D00000);        // overlay (NBIN*BIN_CAP*4)

    k_init<<<1, 128, 0, stream>>>(tailp);

    // gemm1 (x @ W1 -> hbufA, unscaled)  ||  LDS-binned edge partition
    k_pre<<<GEMM_BLOCKS + BIN_BLOCKS, 256, 0, stream>>>(ei, x, W1, tailp, part, hbufA);
    // bucket ELL build (byte-offset entries) + deg + fused hbufA scale
    k_bucket<<<NBUCKET, 256, 0, stream>>>(part, tailp, ell, deg, hbufA, hbufB);

    // Layer 1->2: gather(h1') + b1 + relu -> @W2 *dinv -> hbufB
    k_gatherW<<<GW_BLOCKS, 256, 0, stream>>>(hbufA, deg, ell, b1, W2, hbufB);
    // Layer 2->3: -> @W3 *dinv -> hbufA
    k_gatherW<<<GW_BLOCKS, 256, 0, stream>>>(hbufB, deg, ell, b2, W3, hbufA);
    // Layer 3 final: fp32 out
    k_gatherF<<<N_NODES / 4, 256, 0, stream>>>(hbufA, deg, ell, b3, out);
}